// Round 3
// baseline (169.693 us; speedup 1.0000x reference)
//
#include <hip/hip_runtime.h>

// ShiftLayer: out[b,t,c] = in[b, t+off[c], c], off per c%3 = {0: identity, 1: t-1, 2: t+1},
// zero padding at t boundaries. B=8, L=8192, C=384 (divisible by 3), fp32 in/out.
//
// One thread per float4 (4 channels = 16B). Load the matching 16B slot from rows
// t-1, t, t+1 (zeros at the sequence edges), select per component by channel%3.
// Non-temporal stores: output is write-once, keep it out of L2 so the 3x-read
// input stream stays cached. ~201 MB mandatory HBM traffic -> ~30 us floor.

constexpr int kB = 8;
constexpr int kL = 8192;
constexpr int kC = 384;
constexpr int kV = 4;                   // fp32 elements per 16B vector
constexpr int kCV = kC / kV;            // 96 vectors per (b,t) row
constexpr int kRowsPerBatch = kL * kCV; // 786432 vectors per batch

typedef __attribute__((ext_vector_type(4))) float f32x4;

__global__ __launch_bounds__(256) void ShiftLayer_66932770341347_kernel(
    const f32x4* __restrict__ in, f32x4* __restrict__ out) {
  // grid: x covers one batch's L*kCV vectors (exact: 786432/256 = 3072 blocks),
  //       y = batch index. No tail check needed.
  int ix = blockIdx.x * 256 + threadIdx.x;     // [0, 786432)
  int v = ix % kCV;                            // vector index within channel row
  int t = ix / kCV;                            // time index [0, kL)
  long long idx = (long long)blockIdx.y * kRowsPerBatch + ix;

  const f32x4 zero = {0.f, 0.f, 0.f, 0.f};
  f32x4 cur = in[idx];
  f32x4 prev = (t > 0)      ? in[idx - kCV] : zero;
  f32x4 next = (t < kL - 1) ? in[idx + kCV] : zero;

  // Base channel of this vector: c0 = v*4; c0 % 3 == v % 3 (4 ≡ 1 mod 3).
  int m0 = v % 3;

  f32x4 o;
#pragma unroll
  for (int i = 0; i < kV; ++i) {
    int m = m0 + i;                  // (v + i) mod 3, m0+i <= 5
    m = (m >= 3) ? m - 3 : m;
    m = (m >= 3) ? m - 3 : m;
    // m==0 -> identity (cur), m==1 -> read t-1 (prev), m==2 -> read t+1 (next)
    o[i] = (m == 0) ? cur[i] : ((m == 1) ? prev[i] : next[i]);
  }
  __builtin_nontemporal_store(o, &out[idx]);
}

extern "C" void kernel_launch(void* const* d_in, const int* in_sizes, int n_in,
                              void* d_out, int out_size, void* d_ws, size_t ws_size,
                              hipStream_t stream) {
  const f32x4* in = reinterpret_cast<const f32x4*>(d_in[0]);
  f32x4* out = reinterpret_cast<f32x4*>(d_out);

  dim3 grid(kRowsPerBatch / 256, kB, 1);   // (3072, 8)
  ShiftLayer_66932770341347_kernel<<<grid, 256, 0, stream>>>(in, out);
}